// Round 10
// baseline (312.160 us; speedup 1.0000x reference)
//
#include <hip/hip_runtime.h>

// RelativePositionalMask: out[h][j][i] = bias[ sidx(i,j) + tidx(i,j)*32 ][h]
//  sidx = searchsorted_left(spatial_bins, |pos_i - pos_j|) clamped to 31
//  tidx = ((frame_i - frame_j) + 33) >> 1 clamped to [0,32]  (exact for the
//         integer-valued frames and the exact -32..32-step-2 linspace)
// Output (8, 3072, 3072) fp32 = 302 MB -> write-BW bound (~48us ideal @6.3TB/s).
// Bias table is 1056 rows x 32 B = 33 KB -> L1/L2 resident.
//
// Layout: thread owns 4 consecutive i; per (j, head) it stores one float4
// (1 KB contiguous per wave per store instruction). Nontemporal stores keep
// the 302 MB zero-reuse output stream from evicting the bias table.
// NOTE: __builtin_nontemporal_store requires a clang ext-vector type, not
// HIP's float4 struct -> use v4f for the store path.

typedef float v4f __attribute__((ext_vector_type(4)));

constexpr int N     = 3072;
constexpr int NHEAD = 8;
constexpr int NSP   = 32;   // spatial bins
constexpr int NTB   = 33;   // temporal bins
constexpr int IT    = 4;    // i per thread
constexpr int JT    = 8;    // j per block

__global__ __launch_bounds__(256) void rpm_kernel(
    const float* __restrict__ coords,   // (N,3): frame, x, y
    const float* __restrict__ bias,     // (NTB*NSP, NHEAD)
    const float* __restrict__ sbins,    // (NSP)
    float* __restrict__ out)            // (NHEAD, N, N)
{
#pragma clang fp contract(off)
    const int i0 = (blockIdx.x * 256 + threadIdx.x) * IT;  // 4 consecutive i
    const int j0 = blockIdx.y * JT;

    // spatial bins: uniform addresses -> s_load into SGPRs
    float sb[NSP];
#pragma unroll
    for (int k = 0; k < NSP; ++k) sb[k] = sbins[k];

    // 4 rows of coords for this thread: 12 consecutive floats, 16B-aligned
    const v4f c0 = *(const v4f*)(coords + (size_t)i0 * 3 + 0);
    const v4f c1 = *(const v4f*)(coords + (size_t)i0 * 3 + 4);
    const v4f c2 = *(const v4f*)(coords + (size_t)i0 * 3 + 8);
    const float fi_[IT] = {c0.x, c0.w, c1.z, c2.y};
    const float px_[IT] = {c0.y, c1.x, c1.w, c2.z};
    const float py_[IT] = {c0.z, c1.y, c2.x, c2.w};
    int ifr_[IT];
#pragma unroll
    for (int k = 0; k < IT; ++k) ifr_[k] = (int)fi_[k];

    const size_t hs = (size_t)N * N;
    float* const outb = out + i0;

#pragma unroll
    for (int jj = 0; jj < JT; ++jj) {
        const int j = j0 + jj;
        const float fj = coords[j * 3 + 0];   // uniform -> scalar loads
        const float qx = coords[j * 3 + 1];
        const float qy = coords[j * 3 + 2];
        const int jfr = (int)fj;

        v4f b0_[IT], b1_[IT];
#pragma unroll
        for (int k = 0; k < IT; ++k) {
            // exact reference float semantics: separately-rounded squares,
            // plain add (contract off), IEEE sqrt
            const float dx  = px_[k] - qx;
            const float dy  = py_[k] - qy;
            const float dx2 = dx * dx;
            const float dy2 = dy * dy;
            const float d   = sqrtf(dx2 + dy2);

            // searchsorted(side='left') == count(bins < d)
            int sc = 0;
#pragma unroll
            for (int b = 0; b < NSP; ++b) sc += (sb[b] < d) ? 1 : 0;
            if (sc > NSP - 1) sc = NSP - 1;

            int t = (ifr_[k] - jfr + 33) >> 1;
            t = t < 0 ? 0 : (t > NTB - 1 ? NTB - 1 : t);

            const v4f* bp = (const v4f*)(bias + (size_t)(sc + t * NSP) * NHEAD);
            b0_[k] = bp[0];   // heads 0..3
            b1_[k] = bp[1];   // heads 4..7
        }

        // transpose 4 rows x 8 heads -> 8 v4f plane-stores
        float* const o = outb + (size_t)j * N;
        const v4f v0 = {b0_[0].x, b0_[1].x, b0_[2].x, b0_[3].x};
        const v4f v1 = {b0_[0].y, b0_[1].y, b0_[2].y, b0_[3].y};
        const v4f v2 = {b0_[0].z, b0_[1].z, b0_[2].z, b0_[3].z};
        const v4f v3 = {b0_[0].w, b0_[1].w, b0_[2].w, b0_[3].w};
        const v4f v4 = {b1_[0].x, b1_[1].x, b1_[2].x, b1_[3].x};
        const v4f v5 = {b1_[0].y, b1_[1].y, b1_[2].y, b1_[3].y};
        const v4f v6 = {b1_[0].z, b1_[1].z, b1_[2].z, b1_[3].z};
        const v4f v7 = {b1_[0].w, b1_[1].w, b1_[2].w, b1_[3].w};
        __builtin_nontemporal_store(v0, (v4f*)(o + 0 * hs));
        __builtin_nontemporal_store(v1, (v4f*)(o + 1 * hs));
        __builtin_nontemporal_store(v2, (v4f*)(o + 2 * hs));
        __builtin_nontemporal_store(v3, (v4f*)(o + 3 * hs));
        __builtin_nontemporal_store(v4, (v4f*)(o + 4 * hs));
        __builtin_nontemporal_store(v5, (v4f*)(o + 5 * hs));
        __builtin_nontemporal_store(v6, (v4f*)(o + 6 * hs));
        __builtin_nontemporal_store(v7, (v4f*)(o + 7 * hs));
    }
}

extern "C" void kernel_launch(void* const* d_in, const int* in_sizes, int n_in,
                              void* d_out, int out_size, void* d_ws, size_t ws_size,
                              hipStream_t stream) {
    const float* coords = (const float*)d_in[0];
    const float* bias   = (const float*)d_in[1];
    const float* sbins  = (const float*)d_in[2];
    // d_in[3] = temporal_bins: replaced by exact integer formula
    float* out = (float*)d_out;

    dim3 grid(N / (256 * IT), N / JT);   // (3, 384)
    rpm_kernel<<<grid, dim3(256), 0, stream>>>(coords, bias, sbins, out);
}

// Round 11
// 309.984 us; speedup vs baseline: 1.0070x; 1.0070x over previous
//
#include <hip/hip_runtime.h>

// RelativePositionalMask: out[h][j][i] = bias[ sidx(i,j) + tidx(i,j)*32 ][h]
//  sidx = searchsorted_left(spatial_bins, |pos_i - pos_j|) clamped to 31
//  tidx = ((frame_i - frame_j) + 33) >> 1 clamped to [0,32]  (exact for the
//         integer-valued frames and the exact -32..32-step-2 linspace)
// Output (8, 3072, 3072) fp32 = 302 MB -> write-BW bound (~48us @6.3TB/s).
// R10 evidence: harness fill kernels hit 6.2-6.4 TB/s (78% peak) with PLAIN
// stores at 10% occupancy -> store mechanism is fine. Our 312us implies a
// kernel-side pathology. This round removes the two 2x-class suspects:
//   1) nt stores  -> plain stores (match the known-good fill path)
//   2) full 8-way j-unroll VGPR blowup -> unroll 2 + __launch_bounds__(256,4)
//      (caps VGPR at 128, prevents spill-to-scratch / occupancy collapse)
// Math paths byte-identical to the absmax==0.0 run.

typedef float v4f __attribute__((ext_vector_type(4)));

constexpr int N     = 3072;
constexpr int NHEAD = 8;
constexpr int NSP   = 32;   // spatial bins
constexpr int NTB   = 33;   // temporal bins
constexpr int IT    = 4;    // i per thread
constexpr int JT    = 8;    // j per block

__global__ __launch_bounds__(256, 4) void rpm_kernel(
    const float* __restrict__ coords,   // (N,3): frame, x, y
    const float* __restrict__ bias,     // (NTB*NSP, NHEAD)
    const float* __restrict__ sbins,    // (NSP)
    float* __restrict__ out)            // (NHEAD, N, N)
{
#pragma clang fp contract(off)
    const int i0 = (blockIdx.x * 256 + threadIdx.x) * IT;  // 4 consecutive i
    const int j0 = blockIdx.y * JT;

    // spatial bins: uniform addresses -> s_load into SGPRs
    float sb[NSP];
#pragma unroll
    for (int k = 0; k < NSP; ++k) sb[k] = sbins[k];

    // 4 rows of coords for this thread: 12 consecutive floats, 16B-aligned
    const v4f c0 = *(const v4f*)(coords + (size_t)i0 * 3 + 0);
    const v4f c1 = *(const v4f*)(coords + (size_t)i0 * 3 + 4);
    const v4f c2 = *(const v4f*)(coords + (size_t)i0 * 3 + 8);
    const float fi_[IT] = {c0.x, c0.w, c1.z, c2.y};
    const float px_[IT] = {c0.y, c1.x, c1.w, c2.z};
    const float py_[IT] = {c0.z, c1.y, c2.x, c2.w};
    int ifr_[IT];
#pragma unroll
    for (int k = 0; k < IT; ++k) ifr_[k] = (int)fi_[k];

    const size_t hs = (size_t)N * N;
    float* const outb = out + i0;

#pragma unroll 2
    for (int jj = 0; jj < JT; ++jj) {
        const int j = j0 + jj;
        const float fj = coords[j * 3 + 0];   // uniform -> scalar loads
        const float qx = coords[j * 3 + 1];
        const float qy = coords[j * 3 + 2];
        const int jfr = (int)fj;

        v4f b0_[IT], b1_[IT];
#pragma unroll
        for (int k = 0; k < IT; ++k) {
            // exact reference float semantics: separately-rounded squares,
            // plain add (contract off), IEEE sqrt
            const float dx  = px_[k] - qx;
            const float dy  = py_[k] - qy;
            const float dx2 = dx * dx;
            const float dy2 = dy * dy;
            const float d   = sqrtf(dx2 + dy2);

            // searchsorted(side='left') == count(bins < d)
            int sc = 0;
#pragma unroll
            for (int b = 0; b < NSP; ++b) sc += (sb[b] < d) ? 1 : 0;
            if (sc > NSP - 1) sc = NSP - 1;

            int t = (ifr_[k] - jfr + 33) >> 1;
            t = t < 0 ? 0 : (t > NTB - 1 ? NTB - 1 : t);

            const v4f* bp = (const v4f*)(bias + (size_t)(sc + t * NSP) * NHEAD);
            b0_[k] = bp[0];   // heads 0..3
            b1_[k] = bp[1];   // heads 4..7
        }

        // transpose 4 rows x 8 heads -> 8 plain v4f plane-stores
        float* const o = outb + (size_t)j * N;
        const v4f v0 = {b0_[0].x, b0_[1].x, b0_[2].x, b0_[3].x};
        const v4f v1 = {b0_[0].y, b0_[1].y, b0_[2].y, b0_[3].y};
        const v4f v2 = {b0_[0].z, b0_[1].z, b0_[2].z, b0_[3].z};
        const v4f v3 = {b0_[0].w, b0_[1].w, b0_[2].w, b0_[3].w};
        const v4f v4 = {b1_[0].x, b1_[1].x, b1_[2].x, b1_[3].x};
        const v4f v5 = {b1_[0].y, b1_[1].y, b1_[2].y, b1_[3].y};
        const v4f v6 = {b1_[0].z, b1_[1].z, b1_[2].z, b1_[3].z};
        const v4f v7 = {b1_[0].w, b1_[1].w, b1_[2].w, b1_[3].w};
        *(v4f*)(o + 0 * hs) = v0;
        *(v4f*)(o + 1 * hs) = v1;
        *(v4f*)(o + 2 * hs) = v2;
        *(v4f*)(o + 3 * hs) = v3;
        *(v4f*)(o + 4 * hs) = v4;
        *(v4f*)(o + 5 * hs) = v5;
        *(v4f*)(o + 6 * hs) = v6;
        *(v4f*)(o + 7 * hs) = v7;
    }
}

extern "C" void kernel_launch(void* const* d_in, const int* in_sizes, int n_in,
                              void* d_out, int out_size, void* d_ws, size_t ws_size,
                              hipStream_t stream) {
    const float* coords = (const float*)d_in[0];
    const float* bias   = (const float*)d_in[1];
    const float* sbins  = (const float*)d_in[2];
    // d_in[3] = temporal_bins: replaced by exact integer formula
    float* out = (float*)d_out;

    dim3 grid(N / (256 * IT), N / JT);   // (3, 384)
    rpm_kernel<<<grid, dim3(256), 0, stream>>>(coords, bias, sbins, out);
}

// Round 12
// 303.921 us; speedup vs baseline: 1.0271x; 1.0199x over previous
//
#include <hip/hip_runtime.h>

// RelativePositionalMask: out[h][j][i] = bias[ sidx(i,j) + tidx(i,j)*32 ][h]
// Output (8, 3072, 3072) fp32 = 302 MB -> write-BW bound (~48us @6.3TB/s).
//
// R10/R11 evidence: nt-vs-plain stores and unroll depth are NEUTRAL (312->310us).
// Our kernel is absent from the duration-sorted top-5 (all harness fills at
// ~195-200us / 1.21GB) => kernel itself < 198us; reported dur likely includes
// a ~200us poison fill. Best mechanistic account of the kernel-side gap vs the
// 48us floor: random-row bias gathers split into ~19M per-lane L1 transactions
// on the SAME vmem/TA port the store stream needs (~31us of issue serialization
// + unhidden gather latency).
//
// R12 change: stage the full 33.8KB bias table in LDS -> gathers move to the
// DS pipe (overlaps the store stream instead of contending with it), and
// JT 8->4 doubles the grid to 2304 blocks for latency-hiding TLP.
// Math paths byte-identical to the absmax==0.0 runs.

typedef float v4f __attribute__((ext_vector_type(4)));

constexpr int N     = 3072;
constexpr int NHEAD = 8;
constexpr int NSP   = 32;    // spatial bins
constexpr int NTB   = 33;    // temporal bins
constexpr int NROW  = NTB * NSP;   // 1056 bias rows
constexpr int IT    = 4;     // i per thread
constexpr int JT    = 4;     // j per block

__global__ __launch_bounds__(256, 4) void rpm_kernel(
    const float* __restrict__ coords,   // (N,3): frame, x, y
    const float* __restrict__ bias,     // (NROW, NHEAD)
    const float* __restrict__ sbins,    // (NSP)
    float* __restrict__ out)            // (NHEAD, N, N)
{
#pragma clang fp contract(off)
    __shared__ float lds_bias[NROW * NHEAD];   // 33792 B

    // cooperative LDS fill: 2112 v4f chunks across 256 threads
    {
        const v4f* gb = (const v4f*)bias;
        v4f* lb = (v4f*)lds_bias;
        for (int t = threadIdx.x; t < NROW * NHEAD / 4; t += 256) lb[t] = gb[t];
    }

    const int i0 = (blockIdx.x * 256 + threadIdx.x) * IT;  // 4 consecutive i
    const int j0 = blockIdx.y * JT;

    // spatial bins: uniform addresses -> s_load into SGPRs
    float sb[NSP];
#pragma unroll
    for (int k = 0; k < NSP; ++k) sb[k] = sbins[k];

    // 4 rows of coords for this thread: 12 consecutive floats, 16B-aligned
    const v4f c0 = *(const v4f*)(coords + (size_t)i0 * 3 + 0);
    const v4f c1 = *(const v4f*)(coords + (size_t)i0 * 3 + 4);
    const v4f c2 = *(const v4f*)(coords + (size_t)i0 * 3 + 8);
    const float fi_[IT] = {c0.x, c0.w, c1.z, c2.y};
    const float px_[IT] = {c0.y, c1.x, c1.w, c2.z};
    const float py_[IT] = {c0.z, c1.y, c2.x, c2.w};
    int ifr_[IT];
#pragma unroll
    for (int k = 0; k < IT; ++k) ifr_[k] = (int)fi_[k];

    const size_t hs = (size_t)N * N;
    float* const outb = out + i0;

    __syncthreads();   // LDS bias table ready

#pragma unroll 2
    for (int jj = 0; jj < JT; ++jj) {
        const int j = j0 + jj;
        const float fj = coords[j * 3 + 0];   // uniform -> scalar loads
        const float qx = coords[j * 3 + 1];
        const float qy = coords[j * 3 + 2];
        const int jfr = (int)fj;

        v4f b0_[IT], b1_[IT];
#pragma unroll
        for (int k = 0; k < IT; ++k) {
            // exact reference float semantics: separately-rounded squares,
            // plain add (contract off), IEEE sqrt
            const float dx  = px_[k] - qx;
            const float dy  = py_[k] - qy;
            const float dx2 = dx * dx;
            const float dy2 = dy * dy;
            const float d   = sqrtf(dx2 + dy2);

            // searchsorted(side='left') == count(bins < d)
            int sc = 0;
#pragma unroll
            for (int b = 0; b < NSP; ++b) sc += (sb[b] < d) ? 1 : 0;
            if (sc > NSP - 1) sc = NSP - 1;

            int t = (ifr_[k] - jfr + 33) >> 1;
            t = t < 0 ? 0 : (t > NTB - 1 ? NTB - 1 : t);

            // LDS gather: DS pipe, overlaps the vmem store stream
            const v4f* bp = (const v4f*)(lds_bias + (size_t)(sc + t * NSP) * NHEAD);
            b0_[k] = bp[0];   // heads 0..3
            b1_[k] = bp[1];   // heads 4..7
        }

        // transpose 4 rows x 8 heads -> 8 plain v4f plane-stores
        float* const o = outb + (size_t)j * N;
        const v4f v0 = {b0_[0].x, b0_[1].x, b0_[2].x, b0_[3].x};
        const v4f v1 = {b0_[0].y, b0_[1].y, b0_[2].y, b0_[3].y};
        const v4f v2 = {b0_[0].z, b0_[1].z, b0_[2].z, b0_[3].z};
        const v4f v3 = {b0_[0].w, b0_[1].w, b0_[2].w, b0_[3].w};
        const v4f v4 = {b1_[0].x, b1_[1].x, b1_[2].x, b1_[3].x};
        const v4f v5 = {b1_[0].y, b1_[1].y, b1_[2].y, b1_[3].y};
        const v4f v6 = {b1_[0].z, b1_[1].z, b1_[2].z, b1_[3].z};
        const v4f v7 = {b1_[0].w, b1_[1].w, b1_[2].w, b1_[3].w};
        *(v4f*)(o + 0 * hs) = v0;
        *(v4f*)(o + 1 * hs) = v1;
        *(v4f*)(o + 2 * hs) = v2;
        *(v4f*)(o + 3 * hs) = v3;
        *(v4f*)(o + 4 * hs) = v4;
        *(v4f*)(o + 5 * hs) = v5;
        *(v4f*)(o + 6 * hs) = v6;
        *(v4f*)(o + 7 * hs) = v7;
    }
}

extern "C" void kernel_launch(void* const* d_in, const int* in_sizes, int n_in,
                              void* d_out, int out_size, void* d_ws, size_t ws_size,
                              hipStream_t stream) {
    const float* coords = (const float*)d_in[0];
    const float* bias   = (const float*)d_in[1];
    const float* sbins  = (const float*)d_in[2];
    // d_in[3] = temporal_bins: replaced by exact integer formula
    float* out = (float*)d_out;

    dim3 grid(N / (256 * IT), N / JT);   // (3, 768)
    rpm_kernel<<<grid, dim3(256), 0, stream>>>(coords, bias, sbins, out);
}